// Round 6
// baseline (371.454 us; speedup 1.0000x reference)
//
#include <hip/hip_runtime.h>

#define HID 32
#define DLAT 97
#define NPG 100
#define TOPK 30
#define BKT_NODES 128   // nodes per bucket (bucket = dst >> 7)
#define BKT_SHIFT 7
#define NBUCK 1024      // bucket table size (ceil(100000/128)=782 used)
#define CAPF 2432       // fixed slots per bucket region (mean 2048, ~8.5 sigma)
#define CHUNK 8192      // edges per partition block

typedef float f32x4 __attribute__((ext_vector_type(4)));

// raw global_load_dwordx4: issued immediately, NOT tracked by compiler waitcnt.
// Volatile asm order is program order -> 8 back-to-back loads stay in flight.
__device__ __forceinline__ f32x4 gload4(const float* p) {
    f32x4 r;
    asm volatile("global_load_dwordx4 %0, %1, off" : "=v"(r) : "v"(p));
    return r;
}

// ---------- single-pass partition: LDS hist + fixed-region reservation ----------
__global__ __launch_bounds__(256) void binB1_kernel(
    const int* __restrict__ src, const int* __restrict__ dst,
    const float* __restrict__ ew, int* __restrict__ gcursor,
    int2* __restrict__ bedge, int E) {
    __shared__ int hist[NBUCK];      // 4 KB
    __shared__ int lcur[NBUCK];      // 4 KB
    __shared__ int dcache[CHUNK];    // 32 KB
    for (int i = threadIdx.x; i < NBUCK; i += 256) hist[i] = 0;
    __syncthreads();
    int base = blockIdx.x * CHUNK;
    int M = min(E - base, CHUNK);
    for (int i = threadIdx.x; i < M; i += 256) {
        int d = dst[base + i];
        dcache[i] = d;
        atomicAdd(&hist[d >> BKT_SHIFT], 1);
    }
    __syncthreads();
    for (int b = threadIdx.x; b < NBUCK; b += 256) {
        int v = hist[b];
        lcur[b] = b * CAPF + (v ? atomicAdd(&gcursor[b], v) : 0);
    }
    __syncthreads();
    for (int i = threadIdx.x; i < M; i += 256) {
        int d = dcache[i];
        int slot = atomicAdd(&lcur[d >> BKT_SHIFT], 1);
        bedge[slot] = make_int2(src[base + i] | ((d & (BKT_NODES - 1)) << 20),
                                __float_as_int(ew[base + i]));
    }
}

// ---------- one-block exclusive scan of gcursor[1024] -> bstart[1024] ----------
__global__ __launch_bounds__(256) void scan1024_kernel(
    const int* __restrict__ g, int* __restrict__ bstart) {
    __shared__ int sh[256];
    int t = threadIdx.x;
    int t4 = t * 4;
    int a0 = g[t4], a1 = g[t4 + 1], a2 = g[t4 + 2], a3 = g[t4 + 3];
    int tsum = a0 + a1 + a2 + a3;
    sh[t] = tsum;
    __syncthreads();
    for (int off = 1; off < 256; off <<= 1) {
        int tv = (t >= off) ? sh[t - off] : 0;
        __syncthreads();
        sh[t] += tv;
        __syncthreads();
    }
    int e = sh[t] - tsum;   // exclusive prefix of this thread's 4 buckets
    bstart[t4] = e;
    bstart[t4 + 1] = e + a0;
    bstart[t4 + 2] = e + a0 + a1;
    bstart[t4 + 3] = e + a0 + a1 + a2;
}

// ---------- per-bucket: counting sort + dinv + fused xw1 ----------
__global__ __launch_bounds__(256) void sortlocal3_kernel(
    const int2* __restrict__ bedge, const int* __restrict__ gcursor,
    const int* __restrict__ bstart,
    const int* __restrict__ z, const float* __restrict__ z_emb,
    const float* __restrict__ W1, int2* __restrict__ csr,
    int* __restrict__ row_start, int* __restrict__ row_deg,
    float* __restrict__ dinv, float* __restrict__ xw_a, int N) {
    __shared__ int2 LDSe[CAPF];          // 19 KB
    __shared__ int cnt[BKT_NODES];
    __shared__ int sh2[BKT_NODES];
    __shared__ int lc2[BKT_NODES];
    __shared__ int zloc[BKT_NODES];
    __shared__ float wsum[BKT_NODES];
    __shared__ float dloc[BKT_NODES];
    __shared__ float W1L[HID * HID];     // 4 KB

    int b = blockIdx.x, t = threadIdx.x;
    for (int i = t; i < HID * HID; i += 256) W1L[i] = W1[i];
    if (t < BKT_NODES) { cnt[t] = 0; wsum[t] = 0.f; }
    __syncthreads();

    const int begOut = bstart[b];
    const int M = gcursor[b];

    // load bucket edges into LDS + per-node count + weight sum
    for (int i = t; i < M; i += 256) {
        int2 e = bedge[(size_t)b * CAPF + i];
        LDSe[i] = e;
        int nl = (e.x >> 20) & (BKT_NODES - 1);
        atomicAdd(&cnt[nl], 1);
        atomicAdd(&wsum[nl], __int_as_float(e.y));
    }
    __syncthreads();
    int v = 0, excl = 0;
    int n = b * BKT_NODES + t;
    if (t < BKT_NODES) { v = cnt[t]; sh2[t] = v; }
    __syncthreads();
    for (int off = 1; off < BKT_NODES; off <<= 1) {
        int tv = (t >= off && t < BKT_NODES) ? sh2[t - off] : 0;
        __syncthreads();
        if (t < BKT_NODES) sh2[t] += tv;
        __syncthreads();
    }
    if (t < BKT_NODES) {
        excl = sh2[t] - v;
        lc2[t] = excl;
        float di = 1.f / sqrtf(1.f + wsum[t]);
        dloc[t] = di;
        if (n < N) {
            row_start[n] = begOut + excl;
            row_deg[n] = v;
            dinv[n] = di;
            zloc[t] = z[n];
        } else {
            zloc[t] = 0;
        }
    }
    __syncthreads();
    for (int i = t; i < M; i += 256) {
        int2 e = LDSe[i];
        int slot = atomicAdd(&lc2[(e.x >> 20) & (BKT_NODES - 1)], 1);
        csr[begOut + slot] = make_int2(e.x & 0xFFFFF, e.y);
    }
    // fused layer-1 xw (prescaled): xw_a[n][f] = dinv[n]*dot(z_emb[z[n]], W1[:,f])
    int lim = min(BKT_NODES, N - b * BKT_NODES);
    if (lim > 0) {
        for (int idx = t; idx < lim * HID; idx += 256) {
            int nl = idx >> 5, f = idx & 31;
            const float* row = z_emb + (size_t)zloc[nl] * HID;
            float s = 0.f;
#pragma unroll
            for (int k = 0; k < HID; ++k) s += row[k] * W1L[k * HID + f];
            xw_a[(size_t)(b * BKT_NODES + nl) * HID + f] = s * dloc[nl];
        }
    }
}

// ---------------- aggregation: asm-batched gathers, true 8-deep MLP ----------------
// One node per 32-lane half-wave. Lane = (f-block<<2) | edge-slot.
// R22: compiler kept VGPR=32 and serialized gathers (~2-deep) regardless of
// launch_bounds (R21 neutral). Fix: (a) coalesced csr read (lane i reads edge i,
// slots redistributed by 16 shfl), (b) 8 global_load_dwordx4 via volatile inline
// asm + one explicit s_waitcnt vmcnt(0) + sched_barrier(0) (rule #18) -> all 8
// row-gathers genuinely in flight. x[8] live across the wait => VGPR ~60.
template <int MODE>
__global__ __launch_bounds__(256) void agg32y_kernel(
    const int* __restrict__ row_start, const int* __restrict__ row_deg,
    const int2* __restrict__ csr, const float* __restrict__ xw,
    const float* __restrict__ b, const float* __restrict__ dinv,
    const float* __restrict__ Wn, float* __restrict__ cout,
    float* __restrict__ xw_next, int N) {
    __shared__ float WnL[HID * HID];   // 4 KB (MODE 1 uses first 32)
    int t = threadIdx.x;
    if (MODE == 0) {
        for (int i = t; i < HID * HID; i += 256) WnL[i] = Wn[i];
    } else {
        if (t < HID) WnL[t] = Wn[t];
    }
    __syncthreads();
    int tid = blockIdx.x * 256 + t;
    int n = tid >> 5;
    if (n >= N) return;
    int lane = t & 31;
    int eq = lane & 3;
    int f4 = lane & 28;
    // independent loads issued before the dependent gather chain
    int beg = row_start[n];
    int deg = row_deg[n];
    float di = dinv[n];
    float selfv = xw[(size_t)n * HID + lane];
    int end = beg + deg;
    float4 acc = make_float4(0.f, 0.f, 0.f, 0.f);
    for (int i = beg; i < end; i += 32) {
        // coalesced: lane l owns edge i+l (clamped); weight zeroed if OOB
        int e = i + lane;
        int2 ce = csr[min(e, end - 1)];
        float we = (e < end) ? __int_as_float(ce.y) : 0.f;
        int ci = ce.x;
        f32x4 x[8];
        float w[8];
#pragma unroll
        for (int j = 0; j < 8; ++j) {
            int s = 4 * j + eq;                  // slot (j, eq) lives in lane s
            int idx = __shfl(ci, s, 32);
            w[j] = __shfl(we, s, 32);
            x[j] = gload4(xw + (size_t)idx * HID + f4);
        }
        asm volatile("s_waitcnt vmcnt(0)" ::: "memory");
        __builtin_amdgcn_sched_barrier(0);
#pragma unroll
        for (int j = 0; j < 8; ++j) {
            acc.x += w[j] * x[j].x;
            acc.y += w[j] * x[j].y;
            acc.z += w[j] * x[j].z;
            acc.w += w[j] * x[j].w;
        }
    }
    // reduce over the 4 edge-slot lanes of each quad
#pragma unroll
    for (int m = 1; m <= 2; m <<= 1) {
        acc.x += __shfl_xor(acc.x, m, 32);
        acc.y += __shfl_xor(acc.y, m, 32);
        acc.z += __shfl_xor(acc.z, m, 32);
        acc.w += __shfl_xor(acc.w, m, 32);
    }
    // lane wants f = lane: its quad holds cols f4..f4+3; component = eq
    float s = (eq == 0) ? acc.x : (eq == 1) ? acc.y : (eq == 2) ? acc.z : acc.w;
    float outv = tanhf(di * (s + selfv) + b[lane]);
    cout[(size_t)n * HID + lane] = outv;

    if (MODE == 0) {
        float p = 0.f;
#pragma unroll
        for (int k = 0; k < HID; ++k) {
            float ok = __shfl(outv, k, 32);
            p += ok * WnL[k * HID + lane];
        }
        xw_next[(size_t)n * HID + lane] = p * di;
    } else {
        float p = outv * WnL[lane];
        p += __shfl_xor(p, 16, 32);
        p += __shfl_xor(p, 8, 32);
        p += __shfl_xor(p, 4, 32);
        p += __shfl_xor(p, 2, 32);
        p += __shfl_xor(p, 1, 32);
        if (lane == 0) xw_next[n] = p * di;
    }
}

// ---- fused: layer-4 agg + tanh + stable top-30 + CNN/MLP head ----
// concat is 3 column blocks cblk[l][N][32] (l = layer), col 96 = xw4-derived tval.
__global__ __launch_bounds__(256) void topk_head_kernel(
    const int* __restrict__ row_start, const int* __restrict__ row_deg,
    const int2* __restrict__ csr, const float* __restrict__ xw4,
    const float* __restrict__ b4, const float* __restrict__ dinv,
    const float* __restrict__ cblk,
    const float* __restrict__ Wc1, const float* __restrict__ bc1,
    const float* __restrict__ Wc2, const float* __restrict__ bc2,
    const float* __restrict__ Wl1, const float* __restrict__ bl1,
    const float* __restrict__ Wl2, const float* __restrict__ bl2,
    float* __restrict__ out, int N) {
    int g = blockIdx.x;
    int tid = threadIdx.x;  // 256 threads
    __shared__ float v[NPG];
    __shared__ int tidx[TOPK];
    __shared__ float tval[TOPK];
    __shared__ float top[TOPK * DLAT];   // 11.6 KB
    __shared__ float Wc1L[16 * DLAT];    // 6.2 KB
    __shared__ float Wc2L[32 * 16 * 5];  // 10.2 KB
    __shared__ float y1[16 * TOPK];
    __shared__ float y2[16 * 15];
    __shared__ float y3[352];
    __shared__ float r[256];

    // stage conv weights (read once per block; graph-independent broadcast)
    for (int i = tid; i < 16 * DLAT; i += 256) Wc1L[i] = Wc1[i];
    for (int i = tid; i < 32 * 16 * 5; i += 256) Wc2L[i] = Wc2[i];

    // layer-4 agg: predicated 4-deep unroll (tid < 100)
    if (tid < NPG) {
        int n = g * NPG + tid;
        int beg = row_start[n], end = beg + row_deg[n];
        float s0 = 0.f, s1 = 0.f;
        for (int i = beg; i < end; i += 4) {
            int2 e0 = csr[min(i, end - 1)];
            int2 e1 = csr[min(i + 1, end - 1)];
            int2 e2 = csr[min(i + 2, end - 1)];
            int2 e3 = csr[min(i + 3, end - 1)];
            float x0 = xw4[e0.x], x1 = xw4[e1.x], x2 = xw4[e2.x], x3 = xw4[e3.x];
            s0 += __int_as_float(e0.y) * x0;
            if (i + 1 < end) s1 += __int_as_float(e1.y) * x1;
            if (i + 2 < end) s0 += __int_as_float(e2.y) * x2;
            if (i + 3 < end) s1 += __int_as_float(e3.y) * x3;
        }
        v[tid] = tanhf(dinv[n] * ((s0 + s1) + xw4[n]) + b4[0]);
    }
    __syncthreads();
    // stable rank select (matches jnp.argsort(-v): lower index wins ties)
    if (tid < NPG) {
        float vi = v[tid];
        int cnt = 0;
#pragma unroll 4
        for (int j = 0; j < NPG; ++j) {
            float vj = v[j];
            cnt += (vj > vi) || (vj == vi && j < tid);
        }
        if (cnt < TOPK) {
            tidx[cnt] = g * NPG + tid;
            tval[cnt] = vi;
        }
    }
    __syncthreads();

    for (int idx = tid; idx < TOPK * DLAT; idx += 256) {
        int k = idx / DLAT, d = idx - k * DLAT;
        float val;
        if (d == 96) val = tval[k];
        else val = cblk[(size_t)(d >> 5) * N * HID + (size_t)tidx[k] * HID + (d & 31)];
        top[idx] = val;
    }
    __syncthreads();

    // conv1 (LDS-only): y1[c][k] = relu(dot(top[k], Wc1L[c]) + bc1[c])
    for (int idx = tid; idx < 16 * TOPK; idx += 256) {
        int c = idx / TOPK, k = idx % TOPK;
        float s = bc1[c];
        const float* w = Wc1L + c * DLAT;
        const float* t = top + k * DLAT;
#pragma unroll 4
        for (int d = 0; d < DLAT; ++d) s += t[d] * w[d];
        y1[c * TOPK + k] = fmaxf(s, 0.f);
    }
    __syncthreads();

    for (int idx = tid; idx < 16 * 15; idx += 256) {
        int c = idx / 15, j = idx % 15;
        y2[idx] = fmaxf(y1[c * TOPK + 2 * j], y1[c * TOPK + 2 * j + 1]);
    }
    __syncthreads();

    // conv2 (LDS-only)
    for (int idx = tid; idx < 352; idx += 256) {
        int o = idx / 11, t = idx % 11;
        float s = bc2[o];
#pragma unroll
        for (int i = 0; i < 16; ++i) {
#pragma unroll
            for (int k = 0; k < 5; ++k)
                s += Wc2L[(o * 16 + i) * 5 + k] * y2[i * 15 + t + k];
        }
        y3[idx] = fmaxf(s, 0.f);
    }
    __syncthreads();

    // fc1 (352->128) split 2-way: pair (o, o+128) sums halves of d-range
    {
        int half = tid >> 7;          // 0 or 1
        int o = tid & 127;
        int d0 = half * 176;
        float s = (half == 0) ? bl1[o] : 0.f;
#pragma unroll 1
        for (int d = d0; d < d0 + 176; d += 8) {
            float wv[8], yv[8];
#pragma unroll
            for (int j = 0; j < 8; ++j) wv[j] = Wl1[(d + j) * 128 + o];
#pragma unroll
            for (int j = 0; j < 8; ++j) yv[j] = y3[d + j];
#pragma unroll
            for (int j = 0; j < 8; ++j) s += yv[j] * wv[j];
        }
        r[tid] = s;
    }
    __syncthreads();
    if (tid < 128) r[tid] = fmaxf(r[tid] + r[tid + 128], 0.f) * Wl2[tid];
    __syncthreads();
    if (tid < 64) r[tid] += r[tid + 64];
    __syncthreads();
    if (tid == 0) {
        float s = 0.f;
        for (int j = 0; j < 64; ++j) s += r[j];
        out[g] = s + bl2[0];
    }
}

// ---------------- launch ----------------

extern "C" void kernel_launch(void* const* d_in, const int* in_sizes, int n_in,
                              void* d_out, int out_size, void* d_ws, size_t ws_size,
                              hipStream_t stream) {
    const int* z = (const int*)d_in[0];
    const int* ei = (const int*)d_in[1];
    const float* ew = (const float*)d_in[3];
    const float* z_emb = (const float*)d_in[4];
    const float* Wg[4] = {(const float*)d_in[5], (const float*)d_in[7],
                          (const float*)d_in[9], (const float*)d_in[11]};
    const float* bg[4] = {(const float*)d_in[6], (const float*)d_in[8],
                          (const float*)d_in[10], (const float*)d_in[12]};
    const float* Wc1 = (const float*)d_in[13];
    const float* bc1 = (const float*)d_in[14];
    const float* Wc2 = (const float*)d_in[15];
    const float* bc2 = (const float*)d_in[16];
    const float* Wl1 = (const float*)d_in[17];
    const float* bl1 = (const float*)d_in[18];
    const float* Wl2 = (const float*)d_in[19];
    const float* bl2 = (const float*)d_in[20];
    float* out = (float*)d_out;

    const int N = in_sizes[0];
    const int E = in_sizes[1] / 2;
    const int G = out_size;  // 1000 graphs
    const int* src = ei;
    const int* dst = ei + E;

    auto cdiv = [](long long a, long long b) { return (int)((a + b - 1) / b); };
    const int NB = cdiv(E, CHUNK);          // 196 partition blocks
    const int NBKT = cdiv(N, BKT_NODES);    // 782 buckets

    // workspace layout (8B-aligned arrays first)
    char* ws = (char*)d_ws;
    int2* bedge = (int2*)ws;                  ws += sizeof(int2) * (size_t)NBUCK * CAPF;
    int2* csr = (int2*)ws;                    ws += sizeof(int2) * (size_t)E;
    int* gcursor = (int*)ws;                  ws += sizeof(int) * NBUCK;
    int* bstart = (int*)ws;                   ws += sizeof(int) * NBUCK;
    int* row_start = (int*)ws;                ws += sizeof(int) * N;
    int* row_deg = (int*)ws;                  ws += sizeof(int) * N;
    float* dinv = (float*)ws;                 ws += sizeof(float) * N;
    float* xw_a = (float*)ws;                 ws += sizeof(float) * (size_t)N * HID;
    float* cblk = (float*)ws;                 ws += sizeof(float) * (size_t)3 * N * HID;
    float* xw4 = (float*)ws;                  ws += sizeof(float) * N;
    // xw ping-pong: B-buffer aliases bedge (dead after sortlocal3; 12.8MB <= 19.9MB)
    float* xw_b = (float*)bedge;
    float* cb0 = cblk;
    float* cb1 = cblk + (size_t)N * HID;
    float* cb2 = cblk + (size_t)2 * N * HID;

    const int B = 256;

    // partition + bucket-base scan + per-bucket sort (+dinv, xw1 fused)
    hipMemsetAsync(gcursor, 0, sizeof(int) * NBUCK, stream);
    binB1_kernel<<<NB, B, 0, stream>>>(src, dst, ew, gcursor, bedge, E);
    scan1024_kernel<<<1, B, 0, stream>>>(gcursor, bstart);
    sortlocal3_kernel<<<NBKT, B, 0, stream>>>(bedge, gcursor, bstart, z, z_emb, Wg[0],
                                              csr, row_start, row_deg, dinv, xw_a, N);

    // fused agg + next-layer xw chain (1 node per 32-lane half, asm-batched gathers)
    const int AGGB = cdiv((long long)N * 32, B);
    agg32y_kernel<0><<<AGGB, B, 0, stream>>>(row_start, row_deg, csr, xw_a, bg[0], dinv,
                                             Wg[1], cb0, xw_b, N);
    agg32y_kernel<0><<<AGGB, B, 0, stream>>>(row_start, row_deg, csr, xw_b, bg[1], dinv,
                                             Wg[2], cb1, xw_a, N);
    agg32y_kernel<1><<<AGGB, B, 0, stream>>>(row_start, row_deg, csr, xw_a, bg[2], dinv,
                                             Wg[3], cb2, xw4, N);

    // fused layer-4 agg + tanh + top-30 + head (256 threads/block)
    topk_head_kernel<<<G, 256, 0, stream>>>(row_start, row_deg, csr, xw4, bg[3], dinv,
                                            cblk, Wc1, bc1, Wc2, bc2, Wl1, bl1,
                                            Wl2, bl2, out, N);
}

// Round 7
// 344.365 us; speedup vs baseline: 1.0787x; 1.0787x over previous
//
#include <hip/hip_runtime.h>

#define HID 32
#define DLAT 97
#define NPG 100
#define TOPK 30
#define BKT_NODES 128   // nodes per bucket (bucket = dst >> 7)
#define BKT_SHIFT 7
#define NBUCK 1024      // bucket table size (ceil(100000/128)=782 used)
#define CAPF 2432       // fixed slots per bucket region (mean 2048, ~8.5 sigma)
#define CHUNK 8192      // edges per partition block

typedef float f32x4 __attribute__((ext_vector_type(4)));

// raw global_load_dwordx4 via volatile asm: issued in program order, all stay
// in flight until the explicit s_waitcnt (R22; kept for R23).
__device__ __forceinline__ f32x4 gload4(const float* p) {
    f32x4 r;
    asm volatile("global_load_dwordx4 %0, %1, off" : "=v"(r) : "v"(p));
    return r;
}

// ---------- single-pass partition: LDS hist + fixed-region reservation ----------
// R23: 512 threads (was 256). 196 blocks on 256 CUs is grid-limited; 8 waves/block
// restores latency hiding for the atomic+scatter phases.
__global__ __launch_bounds__(512) void binB1_kernel(
    const int* __restrict__ src, const int* __restrict__ dst,
    const float* __restrict__ ew, int* __restrict__ gcursor,
    int2* __restrict__ bedge, int E) {
    __shared__ int hist[NBUCK];      // 4 KB
    __shared__ int lcur[NBUCK];      // 4 KB
    __shared__ int dcache[CHUNK];    // 32 KB
    for (int i = threadIdx.x; i < NBUCK; i += 512) hist[i] = 0;
    __syncthreads();
    int base = blockIdx.x * CHUNK;
    int M = min(E - base, CHUNK);
    for (int i = threadIdx.x; i < M; i += 512) {
        int d = dst[base + i];
        dcache[i] = d;
        atomicAdd(&hist[d >> BKT_SHIFT], 1);
    }
    __syncthreads();
    for (int b = threadIdx.x; b < NBUCK; b += 512) {
        int v = hist[b];
        lcur[b] = b * CAPF + (v ? atomicAdd(&gcursor[b], v) : 0);
    }
    __syncthreads();
    for (int i = threadIdx.x; i < M; i += 512) {
        int d = dcache[i];
        int slot = atomicAdd(&lcur[d >> BKT_SHIFT], 1);
        bedge[slot] = make_int2(src[base + i] | ((d & (BKT_NODES - 1)) << 20),
                                __float_as_int(ew[base + i]));
    }
}

// ---------- one-block exclusive scan of gcursor[1024] -> bstart[1024] ----------
__global__ __launch_bounds__(256) void scan1024_kernel(
    const int* __restrict__ g, int* __restrict__ bstart) {
    __shared__ int sh[256];
    int t = threadIdx.x;
    int t4 = t * 4;
    int a0 = g[t4], a1 = g[t4 + 1], a2 = g[t4 + 2], a3 = g[t4 + 3];
    int tsum = a0 + a1 + a2 + a3;
    sh[t] = tsum;
    __syncthreads();
    for (int off = 1; off < 256; off <<= 1) {
        int tv = (t >= off) ? sh[t - off] : 0;
        __syncthreads();
        sh[t] += tv;
        __syncthreads();
    }
    int e = sh[t] - tsum;   // exclusive prefix of this thread's 4 buckets
    bstart[t4] = e;
    bstart[t4 + 1] = e + a0;
    bstart[t4 + 2] = e + a0 + a1;
    bstart[t4 + 3] = e + a0 + a1 + a2;
}

// ---------- per-bucket: counting sort + dinv + fused xw1 ----------
// R23: 512 threads (was 256) — halves per-block serial iteration counts; R3 PMC
// showed VALUBusy 11% / occupancy 20% (grid 782 ~ 3 blocks/CU, serialization).
__global__ __launch_bounds__(512) void sortlocal3_kernel(
    const int2* __restrict__ bedge, const int* __restrict__ gcursor,
    const int* __restrict__ bstart,
    const int* __restrict__ z, const float* __restrict__ z_emb,
    const float* __restrict__ W1, int2* __restrict__ csr,
    int* __restrict__ row_start, int* __restrict__ row_deg,
    float* __restrict__ dinv, float* __restrict__ xw_a, int N) {
    __shared__ int2 LDSe[CAPF];          // 19 KB
    __shared__ int cnt[BKT_NODES];
    __shared__ int sh2[BKT_NODES];
    __shared__ int lc2[BKT_NODES];
    __shared__ int zloc[BKT_NODES];
    __shared__ float wsum[BKT_NODES];
    __shared__ float dloc[BKT_NODES];
    __shared__ float W1L[HID * HID];     // 4 KB

    int b = blockIdx.x, t = threadIdx.x;
    for (int i = t; i < HID * HID; i += 512) W1L[i] = W1[i];
    if (t < BKT_NODES) { cnt[t] = 0; wsum[t] = 0.f; }
    __syncthreads();

    const int begOut = bstart[b];
    const int M = gcursor[b];

    // load bucket edges into LDS + per-node count + weight sum
    for (int i = t; i < M; i += 512) {
        int2 e = bedge[(size_t)b * CAPF + i];
        LDSe[i] = e;
        int nl = (e.x >> 20) & (BKT_NODES - 1);
        atomicAdd(&cnt[nl], 1);
        atomicAdd(&wsum[nl], __int_as_float(e.y));
    }
    __syncthreads();
    int v = 0, excl = 0;
    int n = b * BKT_NODES + t;
    if (t < BKT_NODES) { v = cnt[t]; sh2[t] = v; }
    __syncthreads();
    for (int off = 1; off < BKT_NODES; off <<= 1) {
        int tv = (t >= off && t < BKT_NODES) ? sh2[t - off] : 0;
        __syncthreads();
        if (t < BKT_NODES) sh2[t] += tv;
        __syncthreads();
    }
    if (t < BKT_NODES) {
        excl = sh2[t] - v;
        lc2[t] = excl;
        float di = 1.f / sqrtf(1.f + wsum[t]);
        dloc[t] = di;
        if (n < N) {
            row_start[n] = begOut + excl;
            row_deg[n] = v;
            dinv[n] = di;
            zloc[t] = z[n];
        } else {
            zloc[t] = 0;
        }
    }
    __syncthreads();
    for (int i = t; i < M; i += 512) {
        int2 e = LDSe[i];
        int slot = atomicAdd(&lc2[(e.x >> 20) & (BKT_NODES - 1)], 1);
        csr[begOut + slot] = make_int2(e.x & 0xFFFFF, e.y);
    }
    // fused layer-1 xw (prescaled): xw_a[n][f] = dinv[n]*dot(z_emb[z[n]], W1[:,f])
    int lim = min(BKT_NODES, N - b * BKT_NODES);
    if (lim > 0) {
        for (int idx = t; idx < lim * HID; idx += 512) {
            int nl = idx >> 5, f = idx & 31;
            const float* row = z_emb + (size_t)zloc[nl] * HID;
            float s = 0.f;
#pragma unroll
            for (int k = 0; k < HID; ++k) s += row[k] * W1L[k * HID + f];
            xw_a[(size_t)(b * BKT_NODES + nl) * HID + f] = s * dloc[nl];
        }
    }
}

// ---------------- aggregation: asm-batched gathers + clamp-quad skip ----------------
// One node per 32-lane half-wave. Lane = (f-block<<2) | edge-slot.
// R23 theory: agg is pinned at the fabric fill ceiling (FETCH 89.6MB = 8 XCD x
// 12.8MB working set at ~1.5 TB/s = 59.7us = measured). Clamp-quad skip (jmax)
// halves gather instrs at deg~16; predicted dur UNCHANGED (skipped loads were
// same-line L2 hits, not fabric bytes) — controlled test of the BW-ceiling theory.
template <int MODE>
__global__ __launch_bounds__(256) void agg32z_kernel(
    const int* __restrict__ row_start, const int* __restrict__ row_deg,
    const int2* __restrict__ csr, const float* __restrict__ xw,
    const float* __restrict__ b, const float* __restrict__ dinv,
    const float* __restrict__ Wn, float* __restrict__ cout,
    float* __restrict__ xw_next, int N) {
    __shared__ float WnL[HID * HID];   // 4 KB (MODE 1 uses first 32)
    int t = threadIdx.x;
    if (MODE == 0) {
        for (int i = t; i < HID * HID; i += 256) WnL[i] = Wn[i];
    } else {
        if (t < HID) WnL[t] = Wn[t];
    }
    __syncthreads();
    int tid = blockIdx.x * 256 + t;
    int n = tid >> 5;
    if (n >= N) return;
    int lane = t & 31;
    int eq = lane & 3;
    int f4 = lane & 28;
    int beg = row_start[n];
    int deg = row_deg[n];
    float di = dinv[n];
    float selfv = xw[(size_t)n * HID + lane];
    int end = beg + deg;
    float4 acc = make_float4(0.f, 0.f, 0.f, 0.f);
    for (int i = beg; i < end; i += 32) {
        // coalesced: lane l owns edge i+l (clamped); weight zeroed if OOB
        int e = i + lane;
        int2 ce = csr[min(e, end - 1)];
        float we = (e < end) ? __int_as_float(ce.y) : 0.f;
        int ci = ce.x;
        int jmax = min(8, (end - i + 3) >> 2);   // skip all-clamped quads (w==0)
        f32x4 x[8];
        float w[8];
#pragma unroll
        for (int j = 0; j < 8; ++j) {
            if (j < jmax) {
                int s = 4 * j + eq;              // slot (j, eq) lives in lane s
                int idx = __shfl(ci, s, 32);
                w[j] = __shfl(we, s, 32);
                x[j] = gload4(xw + (size_t)idx * HID + f4);
            }
        }
        asm volatile("s_waitcnt vmcnt(0)" ::: "memory");
        __builtin_amdgcn_sched_barrier(0);
#pragma unroll
        for (int j = 0; j < 8; ++j) {
            if (j < jmax) {
                acc.x += w[j] * x[j].x;
                acc.y += w[j] * x[j].y;
                acc.z += w[j] * x[j].z;
                acc.w += w[j] * x[j].w;
            }
        }
    }
    // reduce over the 4 edge-slot lanes of each quad
#pragma unroll
    for (int m = 1; m <= 2; m <<= 1) {
        acc.x += __shfl_xor(acc.x, m, 32);
        acc.y += __shfl_xor(acc.y, m, 32);
        acc.z += __shfl_xor(acc.z, m, 32);
        acc.w += __shfl_xor(acc.w, m, 32);
    }
    // lane wants f = lane: its quad holds cols f4..f4+3; component = eq
    float s = (eq == 0) ? acc.x : (eq == 1) ? acc.y : (eq == 2) ? acc.z : acc.w;
    float outv = tanhf(di * (s + selfv) + b[lane]);
    cout[(size_t)n * HID + lane] = outv;

    if (MODE == 0) {
        float p = 0.f;
#pragma unroll
        for (int k = 0; k < HID; ++k) {
            float ok = __shfl(outv, k, 32);
            p += ok * WnL[k * HID + lane];
        }
        xw_next[(size_t)n * HID + lane] = p * di;
    } else {
        float p = outv * WnL[lane];
        p += __shfl_xor(p, 16, 32);
        p += __shfl_xor(p, 8, 32);
        p += __shfl_xor(p, 4, 32);
        p += __shfl_xor(p, 2, 32);
        p += __shfl_xor(p, 1, 32);
        if (lane == 0) xw_next[n] = p * di;
    }
}

// ---- fused: layer-4 agg + tanh + stable top-30 + CNN/MLP head ----
// concat is 3 column blocks cblk[l][N][32]; col 96 = xw4-derived tval.
// R23: top-row gather vectorized (float4; cblk rows 128B-aligned) — was 2910
// random scalar loads, now 720 dwordx4.
__global__ __launch_bounds__(256) void topk_head_kernel(
    const int* __restrict__ row_start, const int* __restrict__ row_deg,
    const int2* __restrict__ csr, const float* __restrict__ xw4,
    const float* __restrict__ b4, const float* __restrict__ dinv,
    const float* __restrict__ cblk,
    const float* __restrict__ Wc1, const float* __restrict__ bc1,
    const float* __restrict__ Wc2, const float* __restrict__ bc2,
    const float* __restrict__ Wl1, const float* __restrict__ bl1,
    const float* __restrict__ Wl2, const float* __restrict__ bl2,
    float* __restrict__ out, int N) {
    int g = blockIdx.x;
    int tid = threadIdx.x;  // 256 threads
    __shared__ float v[NPG];
    __shared__ int tidx[TOPK];
    __shared__ float tval[TOPK];
    __shared__ float top[TOPK * DLAT];   // 11.6 KB
    __shared__ float Wc1L[16 * DLAT];    // 6.2 KB
    __shared__ float Wc2L[32 * 16 * 5];  // 10.2 KB
    __shared__ float y1[16 * TOPK];
    __shared__ float y2[16 * 15];
    __shared__ float y3[352];
    __shared__ float r[256];

    // stage conv weights (read once per block; graph-independent broadcast)
    for (int i = tid; i < 16 * DLAT; i += 256) Wc1L[i] = Wc1[i];
    for (int i = tid; i < 32 * 16 * 5; i += 256) Wc2L[i] = Wc2[i];

    // layer-4 agg: predicated 4-deep unroll (tid < 100)
    if (tid < NPG) {
        int n = g * NPG + tid;
        int beg = row_start[n], end = beg + row_deg[n];
        float s0 = 0.f, s1 = 0.f;
        for (int i = beg; i < end; i += 4) {
            int2 e0 = csr[min(i, end - 1)];
            int2 e1 = csr[min(i + 1, end - 1)];
            int2 e2 = csr[min(i + 2, end - 1)];
            int2 e3 = csr[min(i + 3, end - 1)];
            float x0 = xw4[e0.x], x1 = xw4[e1.x], x2 = xw4[e2.x], x3 = xw4[e3.x];
            s0 += __int_as_float(e0.y) * x0;
            if (i + 1 < end) s1 += __int_as_float(e1.y) * x1;
            if (i + 2 < end) s0 += __int_as_float(e2.y) * x2;
            if (i + 3 < end) s1 += __int_as_float(e3.y) * x3;
        }
        v[tid] = tanhf(dinv[n] * ((s0 + s1) + xw4[n]) + b4[0]);
    }
    __syncthreads();
    // stable rank select (matches jnp.argsort(-v): lower index wins ties)
    if (tid < NPG) {
        float vi = v[tid];
        int cnt = 0;
#pragma unroll 4
        for (int j = 0; j < NPG; ++j) {
            float vj = v[j];
            cnt += (vj > vi) || (vj == vi && j < tid);
        }
        if (cnt < TOPK) {
            tidx[cnt] = g * NPG + tid;
            tval[cnt] = vi;
        }
    }
    __syncthreads();

    // vectorized top-row gather: 30 rows x (3 blocks x 8 float4) + col 96
    for (int idx = tid; idx < TOPK * 24; idx += 256) {
        int k = idx / 24, q = idx - k * 24;
        int l = q >> 3, fq = q & 7;
        const float4 val =
            *(const float4*)(cblk + (size_t)l * N * HID + (size_t)tidx[k] * HID + fq * 4);
        float* dst = top + k * DLAT + l * HID + fq * 4;
        dst[0] = val.x; dst[1] = val.y; dst[2] = val.z; dst[3] = val.w;
    }
    if (tid < TOPK) top[tid * DLAT + 96] = tval[tid];
    __syncthreads();

    // conv1 (LDS-only): y1[c][k] = relu(dot(top[k], Wc1L[c]) + bc1[c])
    for (int idx = tid; idx < 16 * TOPK; idx += 256) {
        int c = idx / TOPK, k = idx % TOPK;
        float s = bc1[c];
        const float* w = Wc1L + c * DLAT;
        const float* t = top + k * DLAT;
#pragma unroll 4
        for (int d = 0; d < DLAT; ++d) s += t[d] * w[d];
        y1[c * TOPK + k] = fmaxf(s, 0.f);
    }
    __syncthreads();

    for (int idx = tid; idx < 16 * 15; idx += 256) {
        int c = idx / 15, j = idx % 15;
        y2[idx] = fmaxf(y1[c * TOPK + 2 * j], y1[c * TOPK + 2 * j + 1]);
    }
    __syncthreads();

    // conv2 (LDS-only)
    for (int idx = tid; idx < 352; idx += 256) {
        int o = idx / 11, t = idx % 11;
        float s = bc2[o];
#pragma unroll
        for (int i = 0; i < 16; ++i) {
#pragma unroll
            for (int k = 0; k < 5; ++k)
                s += Wc2L[(o * 16 + i) * 5 + k] * y2[i * 15 + t + k];
        }
        y3[idx] = fmaxf(s, 0.f);
    }
    __syncthreads();

    // fc1 (352->128) split 2-way: pair (o, o+128) sums halves of d-range
    {
        int half = tid >> 7;          // 0 or 1
        int o = tid & 127;
        int d0 = half * 176;
        float s = (half == 0) ? bl1[o] : 0.f;
#pragma unroll 1
        for (int d = d0; d < d0 + 176; d += 8) {
            float wv[8], yv[8];
#pragma unroll
            for (int j = 0; j < 8; ++j) wv[j] = Wl1[(d + j) * 128 + o];
#pragma unroll
            for (int j = 0; j < 8; ++j) yv[j] = y3[d + j];
#pragma unroll
            for (int j = 0; j < 8; ++j) s += yv[j] * wv[j];
        }
        r[tid] = s;
    }
    __syncthreads();
    if (tid < 128) r[tid] = fmaxf(r[tid] + r[tid + 128], 0.f) * Wl2[tid];
    __syncthreads();
    if (tid < 64) r[tid] += r[tid + 64];
    __syncthreads();
    if (tid == 0) {
        float s = 0.f;
        for (int j = 0; j < 64; ++j) s += r[j];
        out[g] = s + bl2[0];
    }
}

// ---------------- launch ----------------

extern "C" void kernel_launch(void* const* d_in, const int* in_sizes, int n_in,
                              void* d_out, int out_size, void* d_ws, size_t ws_size,
                              hipStream_t stream) {
    const int* z = (const int*)d_in[0];
    const int* ei = (const int*)d_in[1];
    const float* ew = (const float*)d_in[3];
    const float* z_emb = (const float*)d_in[4];
    const float* Wg[4] = {(const float*)d_in[5], (const float*)d_in[7],
                          (const float*)d_in[9], (const float*)d_in[11]};
    const float* bg[4] = {(const float*)d_in[6], (const float*)d_in[8],
                          (const float*)d_in[10], (const float*)d_in[12]};
    const float* Wc1 = (const float*)d_in[13];
    const float* bc1 = (const float*)d_in[14];
    const float* Wc2 = (const float*)d_in[15];
    const float* bc2 = (const float*)d_in[16];
    const float* Wl1 = (const float*)d_in[17];
    const float* bl1 = (const float*)d_in[18];
    const float* Wl2 = (const float*)d_in[19];
    const float* bl2 = (const float*)d_in[20];
    float* out = (float*)d_out;

    const int N = in_sizes[0];
    const int E = in_sizes[1] / 2;
    const int G = out_size;  // 1000 graphs
    const int* src = ei;
    const int* dst = ei + E;

    auto cdiv = [](long long a, long long b) { return (int)((a + b - 1) / b); };
    const int NB = cdiv(E, CHUNK);          // 196 partition blocks
    const int NBKT = cdiv(N, BKT_NODES);    // 782 buckets

    // workspace layout (8B-aligned arrays first)
    char* ws = (char*)d_ws;
    int2* bedge = (int2*)ws;                  ws += sizeof(int2) * (size_t)NBUCK * CAPF;
    int2* csr = (int2*)ws;                    ws += sizeof(int2) * (size_t)E;
    int* gcursor = (int*)ws;                  ws += sizeof(int) * NBUCK;
    int* bstart = (int*)ws;                   ws += sizeof(int) * NBUCK;
    int* row_start = (int*)ws;                ws += sizeof(int) * N;
    int* row_deg = (int*)ws;                  ws += sizeof(int) * N;
    float* dinv = (float*)ws;                 ws += sizeof(float) * N;
    float* xw_a = (float*)ws;                 ws += sizeof(float) * (size_t)N * HID;
    float* cblk = (float*)ws;                 ws += sizeof(float) * (size_t)3 * N * HID;
    float* xw4 = (float*)ws;                  ws += sizeof(float) * N;
    // xw ping-pong: B-buffer aliases bedge (dead after sortlocal3; 12.8MB <= 19.9MB)
    float* xw_b = (float*)bedge;
    float* cb0 = cblk;
    float* cb1 = cblk + (size_t)N * HID;
    float* cb2 = cblk + (size_t)2 * N * HID;

    // partition + bucket-base scan + per-bucket sort (+dinv, xw1 fused)
    hipMemsetAsync(gcursor, 0, sizeof(int) * NBUCK, stream);
    binB1_kernel<<<NB, 512, 0, stream>>>(src, dst, ew, gcursor, bedge, E);
    scan1024_kernel<<<1, 256, 0, stream>>>(gcursor, bstart);
    sortlocal3_kernel<<<NBKT, 512, 0, stream>>>(bedge, gcursor, bstart, z, z_emb, Wg[0],
                                                csr, row_start, row_deg, dinv, xw_a, N);

    // fused agg + next-layer xw chain (1 node per 32-lane half, asm-batched gathers)
    const int AGGB = cdiv((long long)N * 32, 256);
    agg32z_kernel<0><<<AGGB, 256, 0, stream>>>(row_start, row_deg, csr, xw_a, bg[0],
                                               dinv, Wg[1], cb0, xw_b, N);
    agg32z_kernel<0><<<AGGB, 256, 0, stream>>>(row_start, row_deg, csr, xw_b, bg[1],
                                               dinv, Wg[2], cb1, xw_a, N);
    agg32z_kernel<1><<<AGGB, 256, 0, stream>>>(row_start, row_deg, csr, xw_a, bg[2],
                                               dinv, Wg[3], cb2, xw4, N);

    // fused layer-4 agg + tanh + top-30 + head (256 threads/block)
    topk_head_kernel<<<G, 256, 0, stream>>>(row_start, row_deg, csr, xw4, bg[3], dinv,
                                            cblk, Wc1, bc1, Wc2, bc2, Wl1, bl1,
                                            Wl2, bl2, out, N);
}